// Round 1
// baseline (309.298 us; speedup 1.0000x reference)
//
#include <hip/hip_runtime.h>

#define TPB 256
#define RED_NB 2048

// Gaussian kernel, sigma=1.1, ksize=5 (precomputed, normalized)
#define K0 0.0707663f
#define K1 0.2444606f
#define K2 0.3695462f

// jnp.gradient: central diff interior, one-sided first order at edges.
__device__ __forceinline__ float cgrad(const float* __restrict__ p, int pos, int n, long s) {
    if (pos == 0)     return p[s] - p[0];
    if (pos == n - 1) return p[0] - p[-s];
    return 0.5f * (p[s] - p[-s]);
}

// Direct trilinear resize with align_corners=True. in: (BC, n,n,n) -> out: (BC, m,m,m)
__global__ void resize3d_kernel(const float* __restrict__ in, float* __restrict__ out,
                                int BC, int n, int m, float ratio) {
    long total = (long)BC * m * m * m;
    long idx = (long)blockIdx.x * blockDim.x + threadIdx.x;
    if (idx >= total) return;
    int z = (int)(idx % m); long r = idx / m;
    int y = (int)(r % m);   r /= m;
    int x = (int)(r % m);   int bc = (int)(r / m);

    float cx = (float)x * ratio, cy = (float)y * ratio, cz = (float)z * ratio;
    int x0 = min((int)cx, n - 1), y0 = min((int)cy, n - 1), z0 = min((int)cz, n - 1);
    float wx = cx - (float)x0, wy = cy - (float)y0, wz = cz - (float)z0;
    int x1 = min(x0 + 1, n - 1), y1 = min(y0 + 1, n - 1), z1 = min(z0 + 1, n - 1);

    const float* p = in + (long)bc * n * n * n;
    long sx = (long)n * n;
#define AT(xi, yi, zi) p[(long)(xi) * sx + (long)(yi) * n + (zi)]
    float c00 = AT(x0, y0, z0) * (1.f - wz) + AT(x0, y0, z1) * wz;
    float c01 = AT(x0, y1, z0) * (1.f - wz) + AT(x0, y1, z1) * wz;
    float c10 = AT(x1, y0, z0) * (1.f - wz) + AT(x1, y0, z1) * wz;
    float c11 = AT(x1, y1, z0) * (1.f - wz) + AT(x1, y1, z1) * wz;
#undef AT
    float c0 = c00 * (1.f - wy) + c01 * wy;
    float c1 = c10 * (1.f - wy) + c11 * wy;
    out[idx] = c0 * (1.f - wx) + c1 * wx;
}

// image (B, n,n,n) -> gradient magnitude (B, n,n,n)
__global__ void gradmag_kernel(const float* __restrict__ img, float* __restrict__ g,
                               int B, int n) {
    long n3 = (long)n * n * n;
    long total = (long)B * n3;
    long idx = (long)blockIdx.x * blockDim.x + threadIdx.x;
    if (idx >= total) return;
    int z = (int)(idx % n); long r = idx / n;
    int y = (int)(r % n);   r /= n;
    int x = (int)(r % n);

    const float* p = img + idx;
    float gx = cgrad(p, x, n, (long)n * n);
    float gy = cgrad(p, y, n, n);
    float gz = cgrad(p, z, n, 1);
    g[idx] = sqrtf(gx * gx + gy * gy + gz * gz);
}

// 5-tap blur along one axis, reflect padding (no edge repeat): j<0 -> -j, j>=n -> 2n-2-j
__global__ void blur_kernel(const float* __restrict__ in, float* __restrict__ out,
                            int B, int n, int axis) {
    long n3 = (long)n * n * n;
    long total = (long)B * n3;
    long idx = (long)blockIdx.x * blockDim.x + threadIdx.x;
    if (idx >= total) return;
    int z = (int)(idx % n); long r = idx / n;
    int y = (int)(r % n);   r /= n;
    int x = (int)(r % n);

    int pos; long s;
    if (axis == 0)      { pos = x; s = (long)n * n; }
    else if (axis == 1) { pos = y; s = n; }
    else                { pos = z; s = 1; }

    const float* base = in + idx - (long)pos * s;
    const float K[5] = {K0, K1, K2, K1, K0};
    float acc = 0.f;
#pragma unroll
    for (int t = 0; t < 5; ++t) {
        int j = pos + t - 2;
        j = (j < 0) ? -j : ((j >= n) ? 2 * n - 2 - j : j);
        acc += K[t] * base[(long)j * s];
    }
    out[idx] = acc;
}

// Lame strain energy, weighted, block-reduced into partial[blockIdx.x]
__global__ void energy_kernel(const float* __restrict__ def, const float* __restrict__ ig,
                              float* __restrict__ partial, int B, int n) {
    long n3 = (long)n * n * n;
    long total = (long)B * n3;
    float lsum = 0.f;
    for (long idx = (long)blockIdx.x * blockDim.x + threadIdx.x; idx < total;
         idx += (long)gridDim.x * blockDim.x) {
        int z = (int)(idx % n); long r = idx / n;
        int y = (int)(r % n);   r /= n;
        int x = (int)(r % n);   int b = (int)(r / n);
        long sp = ((long)x * n + y) * n + z;

        const float* u = def + (long)b * 3 * n3 + sp;
        const float* v = u + n3;
        const float* w = u + 2 * n3;
        long sx = (long)n * n;

        float ux = cgrad(u, x, n, sx), uy = cgrad(u, y, n, n), uz = cgrad(u, z, n, 1);
        float vx = cgrad(v, x, n, sx), vy = cgrad(v, y, n, n), vz = cgrad(v, z, n, 1);
        float wx = cgrad(w, x, n, sx), wy = cgrad(w, y, n, n), wz = cgrad(w, z, n, 1);

        float igv = ig[(long)b * n3 + sp];
        float lam = fminf(fmaxf(1.0f + 2.0f * igv, 0.1f), 10.0f);
        float mu  = fminf(fmaxf(0.5f + 1.0f * igv, 0.1f), 10.0f);
        float wt  = 1.0f + 5.0f * igv;

        float Exx = ux, Eyy = vy, Ezz = wz;
        float Exy = 0.5f * (uy + vx);
        float Exz = 0.5f * (uz + wx);
        float Eyz = 0.5f * (vz + wy);
        float tr = Exx + Eyy + Ezz;
        float e = 0.5f * lam * tr * tr +
                  mu * (Exx * Exx + Eyy * Eyy + Ezz * Ezz +
                        2.0f * (Exy * Exy + Exz * Exz + Eyz * Eyz));
        lsum += wt * e;
    }
    __shared__ float sm[TPB];
    sm[threadIdx.x] = lsum;
    __syncthreads();
    for (int s = TPB / 2; s > 0; s >>= 1) {
        if (threadIdx.x < s) sm[threadIdx.x] += sm[threadIdx.x + s];
        __syncthreads();
    }
    if (threadIdx.x == 0) partial[blockIdx.x] = sm[0];
}

// Combine the 3 scale partial arrays + Jacobian penalty -> out[0]
__global__ void finalize_kernel(const float* __restrict__ partial,
                                const float* __restrict__ def, float* __restrict__ out) {
    __shared__ float sm[TPB];
    const float wts[3] = {1.0f, 0.5f, 0.25f};
    const float invcnt[3] = {1.0f / (2.0f * 160 * 160 * 160),
                             1.0f / (2.0f * 80 * 80 * 80),
                             1.0f / (2.0f * 40 * 40 * 40)};
    float acc = 0.f;
    for (int s = 0; s < 3; ++s) {
        float local = 0.f;
        for (int i = threadIdx.x; i < RED_NB; i += TPB) local += partial[s * RED_NB + i];
        acc += wts[s] * invcnt[s] * local;
    }
    sm[threadIdx.x] = acc;
    __syncthreads();
    for (int s = TPB / 2; s > 0; s >>= 1) {
        if (threadIdx.x < s) sm[threadIdx.x] += sm[threadIdx.x + s];
        __syncthreads();
    }
    if (threadIdx.x == 0) {
        float jac = 0.f;
        const int n = 160;
        long n3 = (long)n * n * n;
        long ctr = ((long)80 * n + 80) * n + 80;
        for (int b = 0; b < 2; ++b) {
            const float* p = def + (long)b * 3 * n3;
            float J[3][3];
            for (int c = 0; c < 3; ++c) {
                const float* q = p + (long)c * n3 + ctr;
                J[c][0] = 0.5f * (q[(long)n * n] - q[-(long)n * n]);
                J[c][1] = 0.5f * (q[n] - q[-n]);
                J[c][2] = 0.5f * (q[1] - q[-1]);
            }
            float det = J[0][0] * (J[1][1] * J[2][2] - J[1][2] * J[2][1])
                      - J[0][1] * (J[1][0] * J[2][2] - J[1][2] * J[2][0])
                      + J[0][2] * (J[1][0] * J[2][1] - J[1][1] * J[2][0]);
            jac += fmaxf(-det, 0.f);
        }
        jac *= 0.5f; // mean over B=2
        out[0] = sm[0] + 0.1f * jac;
    }
}

extern "C" void kernel_launch(void* const* d_in, const int* in_sizes, int n_in,
                              void* d_out, int out_size, void* d_ws, size_t ws_size,
                              hipStream_t stream) {
    const float* D = (const float*)d_in[0];  // (2,3,160,160,160)
    const float* I = (const float*)d_in[1];  // (2,1,160,160,160)
    float* out = (float*)d_out;
    float* ws = (float*)d_ws;

    float* partials = ws;                 // 3 * RED_NB floats
    float* arena = ws + 3 * RED_NB;

    const int B = 2;

    // ---------- scale 0: n = 160 (resize is identity) ----------
    {
        const int n = 160;
        long n3 = (long)n * n * n;
        long S = (long)B * n3;
        float* g = arena;
        float* t = arena + S;
        int blocks = (int)((S + TPB - 1) / TPB);
        gradmag_kernel<<<blocks, TPB, 0, stream>>>(I, g, B, n);
        blur_kernel<<<blocks, TPB, 0, stream>>>(g, t, B, n, 0);
        blur_kernel<<<blocks, TPB, 0, stream>>>(t, g, B, n, 1);
        blur_kernel<<<blocks, TPB, 0, stream>>>(g, t, B, n, 2);
        energy_kernel<<<RED_NB, TPB, 0, stream>>>(D, t, partials + 0 * RED_NB, B, n);
    }

    // ---------- scale 1: n = 80 ----------
    {
        const int nin = 160, n = 80;
        long n3 = (long)n * n * n;
        long S = (long)B * n3;
        float* ds = arena;            // 3*S
        float* is = arena + 3 * S;    // S
        float* g  = arena + 4 * S;    // S
        float* t  = arena + 5 * S;    // S
        float ratio = (float)((nin - 1.0) / (n - 1.0));
        long totD = 3 * S;
        resize3d_kernel<<<(int)((totD + TPB - 1) / TPB), TPB, 0, stream>>>(D, ds, B * 3, nin, n, ratio);
        resize3d_kernel<<<(int)((S + TPB - 1) / TPB), TPB, 0, stream>>>(I, is, B, nin, n, ratio);
        int blocks = (int)((S + TPB - 1) / TPB);
        gradmag_kernel<<<blocks, TPB, 0, stream>>>(is, g, B, n);
        blur_kernel<<<blocks, TPB, 0, stream>>>(g, t, B, n, 0);
        blur_kernel<<<blocks, TPB, 0, stream>>>(t, g, B, n, 1);
        blur_kernel<<<blocks, TPB, 0, stream>>>(g, t, B, n, 2);
        energy_kernel<<<RED_NB, TPB, 0, stream>>>(ds, t, partials + 1 * RED_NB, B, n);
    }

    // ---------- scale 2: n = 40 ----------
    {
        const int nin = 160, n = 40;
        long n3 = (long)n * n * n;
        long S = (long)B * n3;
        float* ds = arena;
        float* is = arena + 3 * S;
        float* g  = arena + 4 * S;
        float* t  = arena + 5 * S;
        float ratio = (float)((nin - 1.0) / (n - 1.0));
        long totD = 3 * S;
        resize3d_kernel<<<(int)((totD + TPB - 1) / TPB), TPB, 0, stream>>>(D, ds, B * 3, nin, n, ratio);
        resize3d_kernel<<<(int)((S + TPB - 1) / TPB), TPB, 0, stream>>>(I, is, B, nin, n, ratio);
        int blocks = (int)((S + TPB - 1) / TPB);
        gradmag_kernel<<<blocks, TPB, 0, stream>>>(is, g, B, n);
        blur_kernel<<<blocks, TPB, 0, stream>>>(g, t, B, n, 0);
        blur_kernel<<<blocks, TPB, 0, stream>>>(t, g, B, n, 1);
        blur_kernel<<<blocks, TPB, 0, stream>>>(g, t, B, n, 2);
        energy_kernel<<<RED_NB, TPB, 0, stream>>>(ds, t, partials + 2 * RED_NB, B, n);
    }

    finalize_kernel<<<1, TPB, 0, stream>>>(partials, D, out);
}

// Round 2
// 213.402 us; speedup vs baseline: 1.4494x; 1.4494x over previous
//
#include <hip/hip_runtime.h>

#define TPB 256
#define RED_NB 2048

// Gaussian kernel, sigma=1.1, ksize=5 (precomputed, normalized)
#define K0 0.0707663f
#define K1 0.2444606f
#define K2 0.3695462f

typedef float f4 __attribute__((ext_vector_type(4)));

__device__ __forceinline__ f4 ld4(const float* __restrict__ p) { return *(const f4*)p; }

// reflect index (no edge repeat): j<0 -> -j, j>=n -> 2n-2-j
__device__ __forceinline__ int rref(int i, int n) {
    return i < 0 ? -i : (i >= n ? 2 * n - 2 - i : i);
}

// -------- trilinear resize, align_corners (scalar; small outputs) --------
__global__ void resize3d_kernel(const float* __restrict__ in, float* __restrict__ out,
                                int BC, int n, int m, float ratio) {
    long total = (long)BC * m * m * m;
    long idx = (long)blockIdx.x * blockDim.x + threadIdx.x;
    if (idx >= total) return;
    int z = (int)(idx % m); long r = idx / m;
    int y = (int)(r % m);   r /= m;
    int x = (int)(r % m);   int bc = (int)(r / m);

    float cx = (float)x * ratio, cy = (float)y * ratio, cz = (float)z * ratio;
    int x0 = min((int)cx, n - 1), y0 = min((int)cy, n - 1), z0 = min((int)cz, n - 1);
    float wx = cx - (float)x0, wy = cy - (float)y0, wz = cz - (float)z0;
    int x1 = min(x0 + 1, n - 1), y1 = min(y0 + 1, n - 1), z1 = min(z0 + 1, n - 1);

    const float* p = in + (long)bc * n * n * n;
    long sx = (long)n * n;
#define AT(xi, yi, zi) p[(long)(xi) * sx + (long)(yi) * n + (zi)]
    float c00 = AT(x0, y0, z0) * (1.f - wz) + AT(x0, y0, z1) * wz;
    float c01 = AT(x0, y1, z0) * (1.f - wz) + AT(x0, y1, z1) * wz;
    float c10 = AT(x1, y0, z0) * (1.f - wz) + AT(x1, y0, z1) * wz;
    float c11 = AT(x1, y1, z0) * (1.f - wz) + AT(x1, y1, z1) * wz;
#undef AT
    float c0 = c00 * (1.f - wy) + c01 * wy;
    float c1 = c10 * (1.f - wy) + c11 * wy;
    out[idx] = c0 * (1.f - wx) + c1 * wx;
}

// -------- gradient magnitude, f4 over z --------
__global__ void gradmag_v4(const float* __restrict__ img, float* __restrict__ g,
                           int B, int n) {
    int nz4 = n >> 2;
    long n2 = (long)n * n, n3 = n2 * n;
    long total = (long)B * n * n * nz4;
    long idx = (long)blockIdx.x * blockDim.x + threadIdx.x;
    if (idx >= total) return;
    int z4 = (int)(idx % nz4); long r = idx / nz4;
    int y = (int)(r % n); r /= n;
    int x = (int)(r % n); int b = (int)(r / n);
    int z = z4 * 4;

    const float* base = img + (long)b * n3;
    const float* rowc = base + (long)x * n2 + (long)y * n;
    f4 cur = ld4(rowc + z);
    f4 prev = (z > 0) ? ld4(rowc + z - 4) : cur;      // unused at z==0 (one-sided)
    f4 next = (z + 4 < n) ? ld4(rowc + z + 4) : cur;  // unused at z==n-1

    int xm = max(x - 1, 0), xp = min(x + 1, n - 1);
    int ym = max(y - 1, 0), yp = min(y + 1, n - 1);
    float hx = (x == 0 || x == n - 1) ? 1.f : 0.5f;
    float hy = (y == 0 || y == n - 1) ? 1.f : 0.5f;
    f4 rxp = ld4(base + (long)xp * n2 + (long)y * n + z);
    f4 rxm = ld4(base + (long)xm * n2 + (long)y * n + z);
    f4 ryp = ld4(base + (long)x * n2 + (long)yp * n + z);
    f4 rym = ld4(base + (long)x * n2 + (long)ym * n + z);

    f4 outv;
#pragma unroll
    for (int j = 0; j < 4; ++j) {
        float c = cur[j];
        float zmv = (j == 0) ? prev[3] : cur[(j == 0) ? 0 : j - 1];
        float zpv = (j == 3) ? next[0] : cur[(j == 3) ? 3 : j + 1];
        int gz = z + j;
        float dz = (gz == 0) ? (zpv - c) : ((gz == n - 1) ? (c - zmv) : 0.5f * (zpv - zmv));
        float dx = hx * (rxp[j] - rxm[j]);
        float dy = hy * (ryp[j] - rym[j]);
        outv[j] = sqrtf(dx * dx + dy * dy + dz * dz);
    }
    *(f4*)(g + (long)b * n3 + (long)x * n2 + (long)y * n + z) = outv;
}

// -------- blur along x (axis=0) or y (axis=1), f4 over z --------
__global__ void blur_xy_v4(const float* __restrict__ in, float* __restrict__ out,
                           int B, int n, int axis) {
    int nz4 = n >> 2;
    long n2 = (long)n * n, n3 = n2 * n;
    long total = (long)B * n * n * nz4;
    long idx = (long)blockIdx.x * blockDim.x + threadIdx.x;
    if (idx >= total) return;
    int z4 = (int)(idx % nz4); long r = idx / nz4;
    int y = (int)(r % n); r /= n;
    int x = (int)(r % n); int b = (int)(r / n);
    int z = z4 * 4;

    int pos; long s; long off_fixed;
    if (axis == 0) { pos = x; s = n2; off_fixed = (long)b * n3 + (long)y * n + z; }
    else           { pos = y; s = n;  off_fixed = (long)b * n3 + (long)x * n2 + z; }

    const float K[5] = {K0, K1, K2, K1, K0};
    f4 acc = {0.f, 0.f, 0.f, 0.f};
#pragma unroll
    for (int t = 0; t < 5; ++t) {
        int q = rref(pos + t - 2, n);
        f4 v = ld4(in + off_fixed + (long)q * s);
        acc += K[t] * v;
    }
    *(f4*)(out + (long)b * n3 + (long)x * n2 + (long)y * n + z) = acc;
}

// -------- blur along z, f4, reflect boundaries --------
__global__ void blur_z_v4(const float* __restrict__ in, float* __restrict__ out,
                          int B, int n) {
    int nz4 = n >> 2;
    long n2 = (long)n * n, n3 = n2 * n;
    long total = (long)B * n * n * nz4;
    long idx = (long)blockIdx.x * blockDim.x + threadIdx.x;
    if (idx >= total) return;
    int z4 = (int)(idx % nz4); long r = idx / nz4;
    int y = (int)(r % n); r /= n;
    int x = (int)(r % n); int b = (int)(r / n);
    int z = z4 * 4;

    const float* rowc = in + (long)b * n3 + (long)x * n2 + (long)y * n;
    f4 cur = ld4(rowc + z);
    f4 prev, next;
    if (z >= 4) prev = ld4(rowc + z - 4);
    else { prev[0] = rowc[4]; prev[1] = rowc[3]; prev[2] = rowc[2]; prev[3] = rowc[1]; }
    if (z + 8 <= n) next = ld4(rowc + z + 4);
    else { next[0] = rowc[n - 2]; next[1] = rowc[n - 3]; next[2] = rowc[n - 4]; next[3] = rowc[n - 5]; }

    float w[12];
#pragma unroll
    for (int i = 0; i < 4; ++i) { w[i] = prev[i]; w[4 + i] = cur[i]; w[8 + i] = next[i]; }

    f4 outv;
#pragma unroll
    for (int j = 0; j < 4; ++j)
        outv[j] = K0 * w[2 + j] + K1 * w[3 + j] + K2 * w[4 + j] + K1 * w[5 + j] + K0 * w[6 + j];

    *(f4*)(out + (long)b * n3 + (long)x * n2 + (long)y * n + z) = outv;
}

// -------- Lame strain energy, f4 over z, block-reduced --------
__global__ void energy_v4(const float* __restrict__ def, const float* __restrict__ ig,
                          float* __restrict__ partial, int B, int n) {
    int nz4 = n >> 2;
    long n2 = (long)n * n, n3 = n2 * n;
    long total = (long)B * n * n * nz4;
    float lsum = 0.f;
    for (long idx = (long)blockIdx.x * blockDim.x + threadIdx.x; idx < total;
         idx += (long)gridDim.x * blockDim.x) {
        int z4 = (int)(idx % nz4); long r = idx / nz4;
        int y = (int)(r % n); r /= n;
        int x = (int)(r % n); int b = (int)(r / n);
        int z = z4 * 4;

        int xm = max(x - 1, 0), xp = min(x + 1, n - 1);
        int ym = max(y - 1, 0), yp = min(y + 1, n - 1);
        float hx = (x == 0 || x == n - 1) ? 1.f : 0.5f;
        float hy = (y == 0 || y == n - 1) ? 1.f : 0.5f;

        const float* base = def + (long)b * 3 * n3;
        long sp = (long)x * n2 + (long)y * n + z;

        f4 CC[3], CP[3], CN[3], RXP[3], RXM[3], RYP[3], RYM[3];
#pragma unroll
        for (int c = 0; c < 3; ++c) {
            const float* rc = base + (long)c * n3 + sp;
            CC[c] = ld4(rc);
            CP[c] = (z > 0) ? ld4(rc - 4) : CC[c];
            CN[c] = (z + 4 < n) ? ld4(rc + 4) : CC[c];
            RXP[c] = ld4(base + (long)c * n3 + (long)xp * n2 + (long)y * n + z);
            RXM[c] = ld4(base + (long)c * n3 + (long)xm * n2 + (long)y * n + z);
            RYP[c] = ld4(base + (long)c * n3 + (long)x * n2 + (long)yp * n + z);
            RYM[c] = ld4(base + (long)c * n3 + (long)x * n2 + (long)ym * n + z);
        }
        f4 igv4 = ld4(ig + (long)b * n3 + sp);

#pragma unroll
        for (int j = 0; j < 4; ++j) {
            int gz = z + j;
            float dX[3], dY[3], dZ[3];
#pragma unroll
            for (int c = 0; c < 3; ++c) {
                float cc = CC[c][j];
                float zmv = (j == 0) ? CP[c][3] : CC[c][(j == 0) ? 0 : j - 1];
                float zpv = (j == 3) ? CN[c][0] : CC[c][(j == 3) ? 3 : j + 1];
                dZ[c] = (gz == 0) ? (zpv - cc)
                                  : ((gz == n - 1) ? (cc - zmv) : 0.5f * (zpv - zmv));
                dX[c] = hx * (RXP[c][j] - RXM[c][j]);
                dY[c] = hy * (RYP[c][j] - RYM[c][j]);
            }
            float igv = igv4[j];
            float lam = fminf(fmaxf(1.0f + 2.0f * igv, 0.1f), 10.0f);
            float mu  = fminf(fmaxf(0.5f + 1.0f * igv, 0.1f), 10.0f);
            float wt  = 1.0f + 5.0f * igv;

            float Exx = dX[0], Eyy = dY[1], Ezz = dZ[2];
            float Exy = 0.5f * (dY[0] + dX[1]);
            float Exz = 0.5f * (dZ[0] + dX[2]);
            float Eyz = 0.5f * (dZ[1] + dY[2]);
            float tr = Exx + Eyy + Ezz;
            float e = 0.5f * lam * tr * tr +
                      mu * (Exx * Exx + Eyy * Eyy + Ezz * Ezz +
                            2.0f * (Exy * Exy + Exz * Exz + Eyz * Eyz));
            lsum += wt * e;
        }
    }
    __shared__ float sm[TPB];
    sm[threadIdx.x] = lsum;
    __syncthreads();
    for (int s = TPB / 2; s > 0; s >>= 1) {
        if (threadIdx.x < s) sm[threadIdx.x] += sm[threadIdx.x + s];
        __syncthreads();
    }
    if (threadIdx.x == 0) partial[blockIdx.x] = sm[0];
}

// -------- combine 3 scale partials + Jacobian penalty -> out[0] --------
__global__ void finalize_kernel(const float* __restrict__ partial,
                                const float* __restrict__ def, float* __restrict__ out) {
    __shared__ float sm[TPB];
    const float wts[3] = {1.0f, 0.5f, 0.25f};
    const float invcnt[3] = {1.0f / (2.0f * 160 * 160 * 160),
                             1.0f / (2.0f * 80 * 80 * 80),
                             1.0f / (2.0f * 40 * 40 * 40)};
    float acc = 0.f;
    for (int s = 0; s < 3; ++s) {
        float local = 0.f;
        for (int i = threadIdx.x; i < RED_NB; i += TPB) local += partial[s * RED_NB + i];
        acc += wts[s] * invcnt[s] * local;
    }
    sm[threadIdx.x] = acc;
    __syncthreads();
    for (int s = TPB / 2; s > 0; s >>= 1) {
        if (threadIdx.x < s) sm[threadIdx.x] += sm[threadIdx.x + s];
        __syncthreads();
    }
    if (threadIdx.x == 0) {
        float jac = 0.f;
        const int n = 160;
        long n3 = (long)n * n * n;
        long ctr = ((long)80 * n + 80) * n + 80;
        for (int b = 0; b < 2; ++b) {
            const float* p = def + (long)b * 3 * n3;
            float J[3][3];
            for (int c = 0; c < 3; ++c) {
                const float* q = p + (long)c * n3 + ctr;
                J[c][0] = 0.5f * (q[(long)n * n] - q[-(long)n * n]);
                J[c][1] = 0.5f * (q[n] - q[-n]);
                J[c][2] = 0.5f * (q[1] - q[-1]);
            }
            float det = J[0][0] * (J[1][1] * J[2][2] - J[1][2] * J[2][1])
                      - J[0][1] * (J[1][0] * J[2][2] - J[1][2] * J[2][0])
                      + J[0][2] * (J[1][0] * J[2][1] - J[1][1] * J[2][0]);
            jac += fmaxf(-det, 0.f);
        }
        jac *= 0.5f; // mean over B=2
        out[0] = sm[0] + 0.1f * jac;
    }
}

extern "C" void kernel_launch(void* const* d_in, const int* in_sizes, int n_in,
                              void* d_out, int out_size, void* d_ws, size_t ws_size,
                              hipStream_t stream) {
    const float* D = (const float*)d_in[0];  // (2,3,160,160,160)
    const float* I = (const float*)d_in[1];  // (2,1,160,160,160)
    float* out = (float*)d_out;
    float* ws = (float*)d_ws;

    float* partials = ws;                  // 3 * RED_NB floats
    float* arena = ws + 3 * RED_NB;

    const int B = 2;
    const long S1 = (long)B * 80 * 80 * 80;
    const long S2 = (long)B * 40 * 40 * 40;

    // disjoint arenas for scales 1 & 2 (scale 0 reuses the whole region afterwards)
    float* ds1 = arena;              // 3*S1
    float* is1 = ds1 + 3 * S1;       // S1
    float* g1  = is1 + S1;           // S1
    float* t1  = g1 + S1;            // S1
    float* ds2 = t1 + S1;            // 3*S2
    float* is2 = ds2 + 3 * S2;       // S2
    float* g2  = is2 + S2;           // S2
    float* t2  = g2 + S2;            // S2

    // ---- all resizes first (D and I each read once; 2nd pass hits L3) ----
    {
        const int nin = 160;
        float r1 = (float)((nin - 1.0) / (80 - 1.0));
        float r2 = (float)((nin - 1.0) / (40 - 1.0));
        long totD1 = 3 * S1, totD2 = 3 * S2;
        resize3d_kernel<<<(int)((totD1 + TPB - 1) / TPB), TPB, 0, stream>>>(D, ds1, B * 3, nin, 80, r1);
        resize3d_kernel<<<(int)((totD2 + TPB - 1) / TPB), TPB, 0, stream>>>(D, ds2, B * 3, nin, 40, r2);
        resize3d_kernel<<<(int)((S1 + TPB - 1) / TPB), TPB, 0, stream>>>(I, is1, B, nin, 80, r1);
        resize3d_kernel<<<(int)((S2 + TPB - 1) / TPB), TPB, 0, stream>>>(I, is2, B, nin, 40, r2);
    }

    // ---- scale 1: n = 80 ----
    {
        const int n = 80;
        long total4 = S1 / 4;
        int blocks = (int)((total4 + TPB - 1) / TPB);
        gradmag_v4<<<blocks, TPB, 0, stream>>>(is1, g1, B, n);
        blur_xy_v4<<<blocks, TPB, 0, stream>>>(g1, t1, B, n, 0);
        blur_xy_v4<<<blocks, TPB, 0, stream>>>(t1, g1, B, n, 1);
        blur_z_v4<<<blocks, TPB, 0, stream>>>(g1, t1, B, n);
        energy_v4<<<RED_NB, TPB, 0, stream>>>(ds1, t1, partials + 1 * RED_NB, B, n);
    }

    // ---- scale 2: n = 40 ----
    {
        const int n = 40;
        long total4 = S2 / 4;
        int blocks = (int)((total4 + TPB - 1) / TPB);
        gradmag_v4<<<blocks, TPB, 0, stream>>>(is2, g2, B, n);
        blur_xy_v4<<<blocks, TPB, 0, stream>>>(g2, t2, B, n, 0);
        blur_xy_v4<<<blocks, TPB, 0, stream>>>(t2, g2, B, n, 1);
        blur_z_v4<<<blocks, TPB, 0, stream>>>(g2, t2, B, n);
        energy_v4<<<RED_NB, TPB, 0, stream>>>(ds2, t2, partials + 2 * RED_NB, B, n);
    }

    // ---- scale 0: n = 160 (identity resize); reuses arena after scales 1-2 done ----
    {
        const int n = 160;
        long S0 = (long)B * n * n * n;
        float* g0 = arena;
        float* t0 = arena + S0;
        long total4 = S0 / 4;
        int blocks = (int)((total4 + TPB - 1) / TPB);
        gradmag_v4<<<blocks, TPB, 0, stream>>>(I, g0, B, n);
        blur_xy_v4<<<blocks, TPB, 0, stream>>>(g0, t0, B, n, 0);
        blur_xy_v4<<<blocks, TPB, 0, stream>>>(t0, g0, B, n, 1);
        blur_z_v4<<<blocks, TPB, 0, stream>>>(g0, t0, B, n);
        energy_v4<<<RED_NB, TPB, 0, stream>>>(D, t0, partials + 0 * RED_NB, B, n);
    }

    finalize_kernel<<<1, TPB, 0, stream>>>(partials, D, out);
}